// Round 1
// 1035.949 us; speedup vs baseline: 1.0624x; 1.0624x over previous
//
#include <hip/hip_runtime.h>
#include <math.h>

#define TOK 4096      // B*S
#define DM 2048
#define SL 2048
#define NHEAD 16
#define DKH 128
#define DFF 8192

typedef float f32x4 __attribute__((ext_vector_type(4)));
typedef __bf16 bf16x8 __attribute__((ext_vector_type(8)));
typedef unsigned short u16x8 __attribute__((ext_vector_type(8)));

__device__ __forceinline__ unsigned short f2bf(float f) {
  unsigned int u = __float_as_uint(f);
  u += 0x7fffu + ((u >> 16) & 1u);
  return (unsigned short)(u >> 16);
}
__device__ __forceinline__ float bf2f(unsigned short h) {
  return __uint_as_float((unsigned int)h << 16);
}

__device__ __forceinline__ void gload_lds16(const void* g, void* l) {
  __builtin_amdgcn_global_load_lds(
      (const __attribute__((address_space(1))) unsigned int*)g,
      (__attribute__((address_space(3))) unsigned int*)l, 16, 0, 0);
}

// ---------------- fused dual layernorm (shared mean/var), fp32 -> bf16 x2 ----
__global__ __launch_bounds__(256) void ln_cast_kernel(
    const float* __restrict__ x, const float* __restrict__ g1,
    const float* __restrict__ be1, const float* __restrict__ g2,
    const float* __restrict__ be2, unsigned short* __restrict__ attn_in,
    unsigned short* __restrict__ ff_in) {
  __shared__ float redS[4], redQ[4];
  long row = blockIdx.x;
  int t = threadIdx.x;
  const float4* xr = (const float4*)(x + row * DM);
  float4 a = xr[t];
  float4 b = xr[t + 256];
  float s = a.x + a.y + a.z + a.w + b.x + b.y + b.z + b.w;
  float q = a.x * a.x + a.y * a.y + a.z * a.z + a.w * a.w +
            b.x * b.x + b.y * b.y + b.z * b.z + b.w * b.w;
  for (int o = 32; o > 0; o >>= 1) {
    s += __shfl_xor(s, o, 64);
    q += __shfl_xor(q, o, 64);
  }
  int wave = t >> 6;
  if ((t & 63) == 0) { redS[wave] = s; redQ[wave] = q; }
  __syncthreads();
  s = redS[0] + redS[1] + redS[2] + redS[3];
  q = redQ[0] + redQ[1] + redQ[2] + redQ[3];
  float mean = s * (1.0f / DM);
  float var = q * (1.0f / DM) - mean * mean;
  float rs = rsqrtf(var + 1e-5f);
  float vals[8] = {a.x, a.y, a.z, a.w, b.x, b.y, b.z, b.w};
  long base = row * DM;
#pragma unroll
  for (int i = 0; i < 8; ++i) {
    int c = (i < 4) ? (4 * t + i) : (1024 + 4 * t + (i - 4));
    float nv = (vals[i] - mean) * rs;
    attn_in[base + c] = f2bf(nv * g1[c] + be1[c]);
    ff_in[base + c] = f2bf(nv * g2[c] + be2[c]);
  }
}

// ---------------- fp32 [R,C] -> bf16 [C,R] ----------------------------------
__global__ __launch_bounds__(256) void transpose_cast(
    const float* __restrict__ in, unsigned short* __restrict__ out, int R, int C) {
  __shared__ float tile[32][33];
  int bx = blockIdx.x << 5;
  int by = blockIdx.y << 5;
  int tx = threadIdx.x & 31, ty = threadIdx.x >> 5;
#pragma unroll
  for (int i = ty; i < 32; i += 8) tile[i][tx] = in[(long)(by + i) * C + bx + tx];
  __syncthreads();
#pragma unroll
  for (int i = ty; i < 32; i += 8)
    out[(long)(bx + i) * R + by + tx] = f2bf(tile[tx][i]);
}

// ---------------- V slice of qkv (bf16) -> v_t[bh][dk][s] --------------------
__global__ __launch_bounds__(256) void transpose_v(
    const unsigned short* __restrict__ qkv, unsigned short* __restrict__ v_t) {
  __shared__ unsigned short tile[32][33];
  int z = blockIdx.z;
  int b = z >> 4, h = z & 15;
  int sx = blockIdx.x << 5;
  int dx = blockIdx.y << 5;
  int tx = threadIdx.x & 31, ty = threadIdx.x >> 5;
  const unsigned short* src = qkv + (long)b * SL * (3 * DM) + 2 * DM + h * DKH;
#pragma unroll
  for (int i = ty; i < 32; i += 8)
    tile[i][tx] = src[(long)(sx + i) * (3 * DM) + dx + tx];
  __syncthreads();
  unsigned short* dst = v_t + (long)z * DKH * SL;
#pragma unroll
  for (int i = ty; i < 32; i += 8)
    dst[(long)(dx + i) * SL + sx + tx] = tile[tx][i];
}

// ---------------- in-place row softmax on bf16 scores ------------------------
__global__ __launch_bounds__(256) void softmax_bf16(unsigned short* __restrict__ sc) {
  __shared__ float red[4];
  long row = blockIdx.x;
  unsigned short* rp = sc + row * (long)SL;
  int t = threadIdx.x, wave = t >> 6;
  u16x8 u = ((const u16x8*)rp)[t];
  const float scale = 0.08838834764831845f;  // 1/sqrt(128)
  float v[8];
  float mx = -1e30f;
#pragma unroll
  for (int i = 0; i < 8; ++i) { v[i] = bf2f(u[i]) * scale; mx = fmaxf(mx, v[i]); }
  for (int o = 32; o > 0; o >>= 1) mx = fmaxf(mx, __shfl_xor(mx, o, 64));
  if ((t & 63) == 0) red[wave] = mx;
  __syncthreads();
  mx = fmaxf(fmaxf(red[0], red[1]), fmaxf(red[2], red[3]));
  __syncthreads();
  float sum = 0.f;
#pragma unroll
  for (int i = 0; i < 8; ++i) { v[i] = __expf(v[i] - mx); sum += v[i]; }
  for (int o = 32; o > 0; o >>= 1) sum += __shfl_xor(sum, o, 64);
  if ((t & 63) == 0) red[wave] = sum;
  __syncthreads();
  float inv = 1.0f / (red[0] + red[1] + red[2] + red[3]);
  u16x8 o;
#pragma unroll
  for (int i = 0; i < 8; ++i) o[i] = f2bf(v[i] * inv);
  ((u16x8*)rp)[t] = o;  // same addr each thread read -> safe in place
}

// ---------------- combine kernels (split-K partial merge) --------------------
__global__ __launch_bounds__(256) void combine_ctx(unsigned short* __restrict__ c0,
                                                   const unsigned short* __restrict__ c1) {
  long i = (long)blockIdx.x * 256 + threadIdx.x;
  u16x8 a = ((const u16x8*)c0)[i];
  u16x8 b = ((const u16x8*)c1)[i];
  u16x8 o;
#pragma unroll
  for (int j = 0; j < 8; ++j) o[j] = f2bf(bf2f(a[j]) + bf2f(b[j]));
  ((u16x8*)c0)[i] = o;
}

__global__ __launch_bounds__(256) void combine_wo(const float* __restrict__ x,
                                                  const unsigned short* __restrict__ p0,
                                                  const unsigned short* __restrict__ p1,
                                                  float* __restrict__ out) {
  long i = ((long)blockIdx.x * 256 + threadIdx.x) * 8;
  u16x8 a = *(const u16x8*)(p0 + i);
  u16x8 b = *(const u16x8*)(p1 + i);
#pragma unroll
  for (int j = 0; j < 8; ++j) out[i + j] = x[i + j] + bf2f(a[j]) + bf2f(b[j]);
}

__global__ __launch_bounds__(256) void combine_ff(const unsigned short* __restrict__ p0,
                                                  const unsigned short* __restrict__ p1,
                                                  const float* __restrict__ ls,
                                                  const float* __restrict__ b2,
                                                  float* __restrict__ out) {
  long i = ((long)blockIdx.x * 256 + threadIdx.x) * 8;
  u16x8 a = *(const u16x8*)(p0 + i);
  u16x8 b = *(const u16x8*)(p1 + i);
#pragma unroll
  for (int j = 0; j < 8; ++j) {
    int col = (int)((i + j) & (DM - 1));
    out[i + j] += ls[col] * (bf2f(a[j]) + bf2f(b[j]) + b2[col]);
  }
}

// ---------------- shared GEMM param block ------------------------------------
struct GemmP {
  const unsigned short* A;
  const unsigned short* B;
  const float* bias;
  const float* xadd;
  const float* lscale;
  float* outf;
  unsigned short* outb;
  int K;               // K per split part
  int lda, ldb, ldc;
  long sAz, sAo, sAi;
  long sBz, sBo, sBi;
  long sCz, sCo, sCi;
  long sKz;            // element stride between split-K partial buffers
  int innerN, zbase, nksplit;
};

// ---------------- generic C = A * B^T bf16 MFMA GEMM (128x128, 2-phase) ------
// Kept for the K=128 / N=128 attention GEMMs (scores, PV).
template <int EPI>
__global__ __launch_bounds__(256, 2) void gemm_bt(GemmP p) {
  __shared__ __align__(16) unsigned short As[128 * 32];
  __shared__ __align__(16) unsigned short Bs[128 * 32];
  const int tid = threadIdx.x;
  const int wave = tid >> 6;
  const int lane = tid & 63;
  const int quad = lane >> 4;
  const int l16 = lane & 15;
  const int wm = (wave >> 1) << 6;
  const int wn = (wave & 1) << 6;
  const long m0 = (long)blockIdx.y << 7;
  const long n0 = (long)blockIdx.x << 7;
  const int kz = blockIdx.z % p.nksplit;
  const int zlog = blockIdx.z / p.nksplit;
  const int zz = p.zbase + zlog;
  const int zq = zz / p.innerN;
  const int zr = zz - zq * p.innerN;
  const long koff = (long)kz * p.K;
  const unsigned short* Ab =
      p.A + (long)zlog * p.sAz + (long)zq * p.sAo + (long)zr * p.sAi + koff;
  const unsigned short* Bb =
      p.B + (long)zlog * p.sBz + (long)zq * p.sBo + (long)zr * p.sBi + koff;
  const long offC =
      (long)zlog * p.sCz + (long)zq * p.sCo + (long)zr * p.sCi + (long)kz * p.sKz;

  f32x4 acc[4][4];
#pragma unroll
  for (int i = 0; i < 4; ++i)
#pragma unroll
    for (int j = 0; j < 4; ++j)
#pragma unroll
      for (int r = 0; r < 4; ++r) acc[i][j][r] = 0.0f;

  const int r0 = tid >> 2;
  const int r1 = r0 + 64;
  const int csw = (((tid & 3) ^ ((r0 >> 1) & 3)) << 3);
  unsigned short* lA0 = As + (long)(tid & ~63) * 8;  // wave-uniform base
  unsigned short* lA1 = As + (long)(256 + (tid & ~63)) * 8;
  unsigned short* lB0 = Bs + (long)(tid & ~63) * 8;
  unsigned short* lB1 = Bs + (long)(256 + (tid & ~63)) * 8;

  for (int k0 = 0; k0 < p.K; k0 += 32) {
    gload_lds16(Ab + (m0 + r0) * (long)p.lda + k0 + csw, lA0);
    gload_lds16(Ab + (m0 + r1) * (long)p.lda + k0 + csw, lA1);
    gload_lds16(Bb + (n0 + r0) * (long)p.ldb + k0 + csw, lB0);
    gload_lds16(Bb + (n0 + r1) * (long)p.ldb + k0 + csw, lB1);
    __syncthreads();
    bf16x8 af[4], bf[4];
#pragma unroll
    for (int i = 0; i < 4; ++i) {
      int rA = wm + i * 16 + l16;
      af[i] = *(const bf16x8*)(As + (((rA << 2) + (quad ^ ((rA >> 1) & 3))) << 3));
      int rB = wn + i * 16 + l16;
      bf[i] = *(const bf16x8*)(Bs + (((rB << 2) + (quad ^ ((rB >> 1) & 3))) << 3));
    }
#pragma unroll
    for (int i = 0; i < 4; ++i)
#pragma unroll
      for (int j = 0; j < 4; ++j)
        acc[i][j] =
            __builtin_amdgcn_mfma_f32_16x16x32_bf16(af[i], bf[j], acc[i][j], 0, 0, 0);
    __syncthreads();
  }

#pragma unroll
  for (int i = 0; i < 4; ++i)
#pragma unroll
    for (int j = 0; j < 4; ++j)
#pragma unroll
      for (int r = 0; r < 4; ++r) {
        long m = m0 + wm + i * 16 + quad * 4 + r;
        long n = n0 + wn + j * 16 + l16;
        long idx = offC + m * (long)p.ldc + n;
        float v = acc[i][j][r];
        if (EPI == 0) {
          p.outb[idx] = f2bf(v);
        } else if (EPI == 2) {
          float u = v + p.bias[n];
          p.outb[idx] = f2bf(0.5f * u * (1.0f + erff(u * 0.70710678118654752f)));
        } else if (EPI == 3) {
          p.outf[idx] = p.xadd[m * (long)p.ldc + n] + v;
        } else {  // 4
          p.outf[idx] += p.lscale[n] * (v + p.bias[n]);
        }
      }
}

// ---------------- 256x256 8-phase bf16 GEMM (T2+T3+T4+T5) --------------------
// BM=BN=256, BK=64, 8 waves (2Mx4N), 128 KiB LDS (2 dbuf x {A,B} x 2 halves).
// Half-tiles interleaved by consumption quadrant:
//   A-half mh: local row r -> global row (r>>6)*128 + mh*64 + (r&63)
//   B-half nh: local row r -> global row (r>>5)*64  + nh*32 + (r&31)
// so phase (mh,nh) reads exactly A-half mh and B-half nh -> staging can rotate
// one half-tile per phase (2 gload_lds) without WAR on the live buffer.
// XOR swizzle: col-block cb (8 bf16) stored at cb ^ (row&7); source address is
// pre-swizzled (linear global_load_lds dest), ds_read_b128 applies same XOR.
// Counted vmcnt(6) steady state (3 half-tiles in flight); vmcnt(4)/vmcnt(0)
// only in the 2-K-tile tail; prologue drains once per block.
template <int EPI>
__global__ __launch_bounds__(512, 2) void gemm256(GemmP p) {
  __shared__ __align__(16) unsigned short As[2 * 2 * 8192];  // 64 KiB
  __shared__ __align__(16) unsigned short Bs[2 * 2 * 8192];  // 64 KiB
  const int tid = threadIdx.x;
  const int wave = tid >> 6;
  const int lane = tid & 63;
  const int quad = lane >> 4;
  const int l16 = lane & 15;
  const int wm = (wave >> 2) << 7;  // 0 / 128
  const int wn = (wave & 3) << 6;   // 0 / 64 / 128 / 192

  // XCD-aware block swizzle (all uses have nwg % 8 == 0 -> bijective)
  const int nwg = gridDim.x * gridDim.y;
  const int orig = blockIdx.y * gridDim.x + blockIdx.x;
  int sw = orig;
  if ((nwg & 7) == 0) sw = (orig & 7) * (nwg >> 3) + (orig >> 3);
  const int bx = sw % gridDim.x;
  const int by = sw / gridDim.x;
  const long m0 = (long)by << 8;
  const long n0 = (long)bx << 8;

  const int kz = blockIdx.z % p.nksplit;
  const int zlog = blockIdx.z / p.nksplit;
  const int zz = p.zbase + zlog;
  const int zq = zz / p.innerN;
  const int zr = zz - zq * p.innerN;
  const long koff = (long)kz * p.K;
  const unsigned short* Ab =
      p.A + (long)zlog * p.sAz + (long)zq * p.sAo + (long)zr * p.sAi + koff;
  const unsigned short* Bb =
      p.B + (long)zlog * p.sBz + (long)zq * p.sBo + (long)zr * p.sBi + koff;
  const long offC =
      (long)zlog * p.sCz + (long)zq * p.sCo + (long)zr * p.sCi + (long)kz * p.sKz;
  const int NT = p.K >> 6;  // K-tiles of 64

  f32x4 acc[8][4];
#pragma unroll
  for (int i = 0; i < 8; ++i)
#pragma unroll
    for (int j = 0; j < 4; ++j)
#pragma unroll
      for (int r = 0; r < 4; ++r) acc[i][j][r] = 0.0f;

  bf16x8 afr[4][2];  // A frags of current mh (4 M-pos x 2 k-slices)
  bf16x8 bfr[4][2];  // B frags of all 4 N-pos (loaded nh=0 @q0, nh=1 @q1)

#define BAR() __builtin_amdgcn_s_barrier()
#define WAIT_LGKM() asm volatile("s_waitcnt lgkmcnt(0)" ::: "memory")
#define VMW(n) asm volatile("s_waitcnt vmcnt(" #n ")" ::: "memory")

  // stage one half-tile: 8 waves x 2 loads x 64 lanes x 16B = 16 KiB
#define STAGE_A(buf, mh, kt)                                                      \
  do {                                                                            \
    unsigned short* dstA = As + (((buf) * 2 + (mh)) << 13) + ((wave << 4) << 6);  \
    const long kk = (long)((kt) << 6);                                            \
    _Pragma("unroll") for (int l = 0; l < 2; ++l) {                               \
      const int rr = (wave << 4) + (l << 3) + (lane >> 3);                        \
      const int gcb = (lane & 7) ^ (rr & 7);                                      \
      const long grow = m0 + (long)(((rr >> 6) << 7) + ((mh) << 6) + (rr & 63));  \
      gload_lds16(Ab + grow * (long)p.lda + kk + (gcb << 3), dstA + (l << 9));    \
    }                                                                             \
  } while (0)

#define STAGE_B(buf, nh, kt)                                                      \
  do {                                                                            \
    unsigned short* dstB = Bs + (((buf) * 2 + (nh)) << 13) + ((wave << 4) << 6);  \
    const long kk = (long)((kt) << 6);                                            \
    _Pragma("unroll") for (int l = 0; l < 2; ++l) {                               \
      const int rr = (wave << 4) + (l << 3) + (lane >> 3);                        \
      const int gcb = (lane & 7) ^ (rr & 7);                                      \
      const long grow = n0 + (long)(((rr >> 5) << 6) + ((nh) << 5) + (rr & 31));  \
      gload_lds16(Bb + grow * (long)p.ldb + kk + (gcb << 3), dstB + (l << 9));    \
    }                                                                             \
  } while (0)

#define LOAD_AF(buf, mh)                                                          \
  do {                                                                            \
    const unsigned short* Ah = As + (((buf) * 2 + (mh)) << 13);                   \
    _Pragma("unroll") for (int i = 0; i < 4; ++i) {                               \
      const int rr = ((wave >> 2) << 6) + (i << 4) + l16;                         \
      _Pragma("unroll") for (int ks = 0; ks < 2; ++ks)                            \
          afr[i][ks] = *(const bf16x8*)(Ah + rr * 64 +                            \
                                        ((((ks << 2) | quad) ^ (rr & 7)) << 3));  \
    }                                                                             \
  } while (0)

#define LOAD_BF(buf, nh)                                                          \
  do {                                                                            \
    const unsigned short* Bh = Bs + (((buf) * 2 + (nh)) << 13);                   \
    _Pragma("unroll") for (int j = 0; j < 2; ++j) {                               \
      const int rr = ((wave & 3) << 5) + (j << 4) + l16;                          \
      _Pragma("unroll") for (int ks = 0; ks < 2; ++ks)                            \
          bfr[(nh) * 2 + j][ks] =                                                 \
              *(const bf16x8*)(Bh + rr * 64 +                                     \
                               ((((ks << 2) | quad) ^ (rr & 7)) << 3));           \
    }                                                                             \
  } while (0)

#define MMA_QUAD(mh, nh)                                                          \
  do {                                                                            \
    __builtin_amdgcn_s_setprio(1);                                                \
    _Pragma("unroll") for (int i = 0; i < 4; ++i)                                 \
        _Pragma("unroll") for (int j = 0; j < 2; ++j)                             \
            _Pragma("unroll") for (int ks = 0; ks < 2; ++ks)                      \
                acc[(mh) * 4 + i][(nh) * 2 + j] =                                 \
                    __builtin_amdgcn_mfma_f32_16x16x32_bf16(                      \
                        afr[i][ks], bfr[(nh) * 2 + j][ks],                        \
                        acc[(mh) * 4 + i][(nh) * 2 + j], 0, 0, 0);                \
    __builtin_amdgcn_s_setprio(0);                                                \
  } while (0)

  // one K-tile = 4 phases; staging rotation:
  //   q0: A1(t+1)  q1: B1(t+1)  q2: A0(t+2)  q3: B0(t+2)
#define KSTEP(t, S1, S2, VMQ)                                                     \
  do {                                                                            \
    const int cur = (t) & 1, nxt = cur ^ 1;                                       \
    LOAD_AF(cur, 0);                                                              \
    LOAD_BF(cur, 0);                                                              \
    if (S1) STAGE_A(nxt, 1, (t) + 1);                                             \
    VMQ; BAR(); WAIT_LGKM();                                                      \
    MMA_QUAD(0, 0);                                                               \
    BAR();                                                                        \
    LOAD_BF(cur, 1);                                                              \
    if (S1) STAGE_B(nxt, 1, (t) + 1);                                             \
    VMQ; BAR(); WAIT_LGKM();                                                      \
    MMA_QUAD(0, 1);                                                               \
    BAR();                                                                        \
    LOAD_AF(cur, 1);                                                              \
    if (S2) STAGE_A(cur, 0, (t) + 2);                                             \
    VMQ; BAR(); WAIT_LGKM();                                                      \
    MMA_QUAD(1, 0);                                                               \
    BAR();                                                                        \
    if (S2) STAGE_B(cur, 0, (t) + 2);                                             \
    VMQ; BAR(); WAIT_LGKM();                                                      \
    MMA_QUAD(1, 1);                                                               \
    BAR();                                                                        \
  } while (0)

  // prologue: K-tile 0 fully + first halves of K-tile 1; full drain once
  STAGE_A(0, 0, 0);
  STAGE_B(0, 0, 0);
  STAGE_A(0, 1, 0);
  STAGE_B(0, 1, 0);
  if (NT > 1) {
    STAGE_A(1, 0, 1);
    STAGE_B(1, 0, 1);
  }
  VMW(0);
  BAR();

  int t = 0;
  for (; t + 2 < NT; ++t) KSTEP(t, true, true, VMW(6));
  if (t + 1 < NT) {
    KSTEP(t, true, false, VMW(4));
    ++t;
  }
  KSTEP(t, false, false, VMW(0));

#undef KSTEP
#undef MMA_QUAD
#undef LOAD_BF
#undef LOAD_AF
#undef STAGE_B
#undef STAGE_A
#undef VMW
#undef WAIT_LGKM
#undef BAR

#pragma unroll
  for (int I = 0; I < 8; ++I)
#pragma unroll
    for (int J = 0; J < 4; ++J)
#pragma unroll
      for (int r = 0; r < 4; ++r) {
        long m = m0 + wm + I * 16 + quad * 4 + r;
        long n = n0 + wn + J * 16 + l16;
        long idx = offC + m * (long)p.ldc + n;
        float v = acc[I][J][r];
        if (EPI == 0) {
          p.outb[idx] = f2bf(v);
        } else if (EPI == 2) {
          float u = v + p.bias[n];
          p.outb[idx] = f2bf(0.5f * u * (1.0f + erff(u * 0.70710678118654752f)));
        } else if (EPI == 3) {
          p.outf[idx] = p.xadd[m * (long)p.ldc + n] + v;
        } else {  // 4
          p.outf[idx] += p.lscale[n] * (v + p.bias[n]);
        }
      }
}

// ----------------------------------------------------------------------------
// Workspace layout (MiB, liveness-overlaid):
//   [0,48)    qkv bf16        (QKV gemm .. end of attention loop)
//   [48,64)   v_t bf16        (after QKV .. end of PV)
//   [64,80)   ff_in bf16      (until FF1)
//   [80,96)   attn_in bf16 -> PV partial C0 (= ctx_bf after combine)
//   [96,112)  PV partial C1   (inside wbuf region; consumed before w_o transpose)
//   [96,128)  wbuf            (one weight at a time; idle during attention loop)
//   [128,..)  scores bf16 chunk*8 MiB (loop) -> P0,P1 bf16 partials 32 MiB (after)
//   h1 overlays [0,64) during FF1/FF2 (qkv/v_t dead).
extern "C" void kernel_launch(void* const* d_in, const int* in_sizes, int n_in,
                              void* d_out, int out_size, void* d_ws, size_t ws_size,
                              hipStream_t stream) {
  const float* x = (const float*)d_in[0];
  const float* w_qkv = (const float*)d_in[2];
  const float* w_o = (const float*)d_in[3];
  const float* g1 = (const float*)d_in[4];
  const float* be1 = (const float*)d_in[5];
  const float* g2 = (const float*)d_in[6];
  const float* be2 = (const float*)d_in[7];
  const float* w1 = (const float*)d_in[8];
  const float* b1 = (const float*)d_in[9];
  const float* w2 = (const float*)d_in[10];
  const float* b2 = (const float*)d_in[11];
  const float* ls = (const float*)d_in[12];
  float* out = (float*)d_out;

  unsigned char* ws = (unsigned char*)d_ws;
  const size_t MiB = 1024 * 1024;
  unsigned short* qkv = (unsigned short*)(ws);
  unsigned short* v_t = (unsigned short*)(ws + 48 * MiB);
  unsigned short* ff_in = (unsigned short*)(ws + 64 * MiB);
  unsigned short* attn_in = (unsigned short*)(ws + 80 * MiB);
  unsigned short* ctxC0 = (unsigned short*)(ws + 80 * MiB);  // = ctx_bf
  unsigned short* ctxC1 = (unsigned short*)(ws + 96 * MiB);
  unsigned short* wbuf = (unsigned short*)(ws + 96 * MiB);
  unsigned short* h1 = (unsigned short*)(ws);
  unsigned short* scores = (unsigned short*)(ws + 128 * MiB);
  unsigned short* P0 = (unsigned short*)(ws + 128 * MiB);
  unsigned short* P1 = (unsigned short*)(ws + 144 * MiB);

  int chunk;
  bool split;
  if (ws_size >= 264 * MiB)      { chunk = 16; split = true; }
  else if (ws_size >= 196 * MiB) { chunk = 8;  split = true; }
  else if (ws_size >= 162 * MiB) { chunk = 4;  split = true; }
  else                           { chunk = 2;  split = false; }

  const long ODM = (long)TOK * DM;  // elements in one [TOK,DM] partial
  dim3 blk(256);
  dim3 blk512(512);

  ln_cast_kernel<<<TOK, blk, 0, stream>>>(x, g1, be1, g2, be2, attn_in, ff_in);

  {  // qkv = attn_in @ w_qkv  (bf16 out) — 256² 8-phase
    transpose_cast<<<dim3(3 * DM / 32, DM / 32), blk, 0, stream>>>(w_qkv, wbuf, DM, 3 * DM);
    GemmP p = {};
    p.A = attn_in; p.B = wbuf; p.outb = qkv;
    p.K = DM; p.lda = DM; p.ldb = DM; p.ldc = 3 * DM;
    p.innerN = 1; p.nksplit = 1;
    gemm256<0><<<dim3(3 * DM / 256, TOK / 256, 1), blk512, 0, stream>>>(p);
  }

  transpose_v<<<dim3(SL / 32, DKH / 32, 32), blk, 0, stream>>>(qkv, v_t);

  for (int c0 = 0; c0 < 32; c0 += chunk) {
    {  // scores[z] = q(bh) @ k(bh)^T  (bf16, scale folded into softmax)
      GemmP p = {};
      p.A = qkv; p.B = qkv + DM; p.outb = scores;
      p.K = DKH; p.lda = 3 * DM; p.ldb = 3 * DM; p.ldc = SL;
      p.sAo = (long)SL * 3 * DM; p.sAi = DKH;
      p.sBo = (long)SL * 3 * DM; p.sBi = DKH;
      p.sCz = (long)SL * SL;
      p.innerN = NHEAD; p.zbase = c0; p.nksplit = 1;
      gemm_bt<0><<<dim3(SL / 128, SL / 128, chunk), blk, 0, stream>>>(p);
    }
    softmax_bf16<<<chunk * SL, blk, 0, stream>>>(scores);
    {  // ctx partials (bh) = P @ V   (split-K x2 into C0/C1, plain bf16 stores)
      GemmP p = {};
      p.A = scores; p.B = v_t; p.outb = ctxC0;
      p.K = split ? SL / 2 : SL; p.lda = SL; p.ldb = SL; p.ldc = DM;
      p.sAz = (long)SL * SL;
      p.sBo = (long)NHEAD * DKH * SL; p.sBi = (long)DKH * SL;
      p.sCo = (long)SL * DM; p.sCi = DKH;
      p.sKz = ODM;
      p.innerN = NHEAD; p.zbase = c0; p.nksplit = split ? 2 : 1;
      gemm_bt<0><<<dim3(DKH / 128, SL / 128, chunk * p.nksplit), blk, 0, stream>>>(p);
    }
  }
  if (split)  // ctx_bf = C0 + C1 (in place into C0)
    combine_ctx<<<(int)(ODM / 2048), blk, 0, stream>>>(ctxC0, ctxC1);

  {  // attn_out = ctx @ w_o ;  out = x + attn_out — 256² 8-phase
    transpose_cast<<<dim3(DM / 32, DM / 32), blk, 0, stream>>>(w_o, wbuf, DM, DM);
    GemmP p = {};
    p.A = ctxC0; p.B = wbuf;
    p.K = split ? DM / 2 : DM; p.lda = DM; p.ldb = DM; p.ldc = DM;
    p.sKz = ODM; p.innerN = 1; p.nksplit = split ? 2 : 1;
    if (split) {
      p.outb = P0;
      gemm256<0><<<dim3(DM / 256, TOK / 256, 2), blk512, 0, stream>>>(p);
      combine_wo<<<(int)(ODM / 2048), blk, 0, stream>>>(x, P0, P1, out);
    } else {
      p.outf = out; p.xadd = x;
      gemm256<3><<<dim3(DM / 256, TOK / 256, 1), blk512, 0, stream>>>(p);
    }
  }
  {  // h1 = gelu(ff_in @ w1 + b1)  (bf16) — overlays qkv/v_t — 256² 8-phase
    transpose_cast<<<dim3(DFF / 32, DM / 32), blk, 0, stream>>>(w1, wbuf, DM, DFF);
    GemmP p = {};
    p.A = ff_in; p.B = wbuf; p.outb = h1; p.bias = b1;
    p.K = DM; p.lda = DM; p.ldb = DM; p.ldc = DFF;
    p.innerN = 1; p.nksplit = 1;
    gemm256<2><<<dim3(DFF / 256, TOK / 256, 1), blk512, 0, stream>>>(p);
  }
  {  // out += layer_scale * (h1 @ w2 + b2) — 256² 8-phase
    transpose_cast<<<dim3(DM / 32, DFF / 32), blk, 0, stream>>>(w2, wbuf, DFF, DM);
    GemmP p = {};
    p.A = h1; p.B = wbuf;
    p.K = split ? DFF / 2 : DFF; p.lda = DFF; p.ldb = DFF; p.ldc = DM;
    p.sKz = ODM; p.innerN = 1; p.nksplit = split ? 2 : 1;
    if (split) {
      p.outb = P0;
      gemm256<0><<<dim3(DM / 256, TOK / 256, 2), blk512, 0, stream>>>(p);
      combine_ff<<<(int)(ODM / 2048), blk, 0, stream>>>(P0, P1, ls, b2, out);
    } else {
      p.outf = out; p.bias = b2; p.lscale = ls;
      gemm256<4><<<dim3(DM / 256, TOK / 256, 1), blk512, 0, stream>>>(p);
    }
  }
}